// Round 1
// baseline (408.707 us; speedup 1.0000x reference)
//
#include <hip/hip_runtime.h>
#include <hip/hip_bf16.h>

#define T_STEPS 256
#define B_COLS  65536
#define GAMMA_F 0.99f

// One thread per column b. Backward scan over time.
// ret_i = acc * (discount[i+1]*g) + reward[i+1]
// acc   = is_last[i] ? target_value[i] : ret_i
// out[i] = (ret_i - value[i])^2 ;  out[T-1] = 0
// is_last[i] = (step_type[i]==2) | (i>0 && (rollout_b[i]!=0 || train_b[i]!=0))
__global__ __launch_bounds__(256) void td_loss_kernel(
    const float* __restrict__ reward,
    const float* __restrict__ discount,
    const float* __restrict__ value,
    const float* __restrict__ target_value,
    const int*   __restrict__ step_type,
    const int*   __restrict__ rollout_b,
    const int*   __restrict__ train_b,
    float*       __restrict__ out)
{
    const unsigned b = blockIdx.x * blockDim.x + threadIdx.x;

    // last row: acc init + zero output
    const unsigned last = (unsigned)(T_STEPS - 1) * B_COLS + b;
    float acc = target_value[last];
    out[last] = 0.0f;

    // hot loop: i = T-2 .. 1 (is_last includes rollout/train)
    #pragma unroll 4
    for (int i = T_STEPS - 2; i >= 1; --i) {
        const unsigned idx  = (unsigned)i * B_COLS + b;
        const unsigned idx1 = idx + B_COLS;

        const float d  = discount[idx1] * GAMMA_F;
        const float r  = reward[idx1];
        const float tv = target_value[idx];
        const float v  = value[idx];
        const int   st = step_type[idx];
        const int   rb = rollout_b[idx];
        const int   tb = train_b[idx];

        const float ret = fmaf(acc, d, r);
        const bool  l   = (st == 2) | (rb != 0) | (tb != 0);
        acc = l ? tv : ret;

        const float diff = ret - v;
        out[idx] = diff * diff;
    }

    // peeled i = 0: b-flag forced false, only step_type matters (but acc not
    // needed afterwards, so we don't even need is_last here)
    {
        const unsigned idx  = b;
        const unsigned idx1 = B_COLS + b;
        const float d   = discount[idx1] * GAMMA_F;
        const float r   = reward[idx1];
        const float ret = fmaf(acc, d, r);
        const float v   = value[idx];
        const float diff = ret - v;
        out[idx] = diff * diff;
    }
}

extern "C" void kernel_launch(void* const* d_in, const int* in_sizes, int n_in,
                              void* d_out, int out_size, void* d_ws, size_t ws_size,
                              hipStream_t stream) {
    const float* reward       = (const float*)d_in[0];
    const float* discount     = (const float*)d_in[1];
    const float* value        = (const float*)d_in[2];
    const float* target_value = (const float*)d_in[3];
    const int*   step_type    = (const int*)d_in[4];
    const int*   rollout_b    = (const int*)d_in[5];
    const int*   train_b      = (const int*)d_in[6];
    float*       out          = (float*)d_out;

    const int block = 256;
    const int grid  = B_COLS / block;  // 256 blocks -> 1 per CU
    td_loss_kernel<<<grid, block, 0, stream>>>(
        reward, discount, value, target_value, step_type, rollout_b, train_b, out);
}

// Round 2
// 401.766 us; speedup vs baseline: 1.0173x; 1.0173x over previous
//
#include <hip/hip_runtime.h>
#include <hip/hip_bf16.h>

#define T_STEPS 256
#define B_COLS  65536
#define GAMMA_F 0.99f

// Backward affine scan, one thread per column.
//   ret_i = acc * (discount[i+1]*g) + reward[i+1]
//   acc   = is_last[i] ? target_value[i] : ret_i
//   out[i]= (ret_i - value[i])^2 ; out[T-1] = 0
//   is_last[i] = (step_type[i]==2) | (i>0 && (rollout_b[i]|train_b[i]))
//
// Round-2 change: explicit load-batching (group of N time-steps) to force
// ~7N independent loads in flight per lane before the compute phase.
// Round-1 compiler output was VGPR=12 (no pipelining) -> latency-bound 153us.

template <int N>
__device__ __forceinline__ float process_group(
    int i_hi, unsigned b, float acc,
    const float* __restrict__ reward,
    const float* __restrict__ discount,
    const float* __restrict__ value,
    const float* __restrict__ target_value,
    const int*   __restrict__ step_type,
    const int*   __restrict__ rollout_b,
    const int*   __restrict__ train_b,
    float*       __restrict__ out)
{
    float d[N], r[N], tv[N], v[N];
    int   st[N], rb[N], tb[N];

    // Phase 1: issue all loads (7*N independent) back-to-back.
#pragma unroll
    for (int j = 0; j < N; ++j) {
        const unsigned idx  = (unsigned)(i_hi - j) * B_COLS + b;
        const unsigned idx1 = idx + B_COLS;
        d[j]  = discount[idx1];
        r[j]  = reward[idx1];
        tv[j] = target_value[idx];
        v[j]  = value[idx];
        st[j] = step_type[idx];
        rb[j] = rollout_b[idx];
        tb[j] = train_b[idx];
    }

    // Phase 2: serial recurrence + stores (cheap).
#pragma unroll
    for (int j = 0; j < N; ++j) {
        const float ret  = fmaf(acc, d[j] * GAMMA_F, r[j]);
        const bool  l    = (st[j] == 2) | (rb[j] != 0) | (tb[j] != 0);
        acc = l ? tv[j] : ret;
        const float diff = ret - v[j];
        out[(unsigned)(i_hi - j) * B_COLS + b] = diff * diff;
    }
    return acc;
}

__global__ __launch_bounds__(256) void td_loss_kernel(
    const float* __restrict__ reward,
    const float* __restrict__ discount,
    const float* __restrict__ value,
    const float* __restrict__ target_value,
    const int*   __restrict__ step_type,
    const int*   __restrict__ rollout_b,
    const int*   __restrict__ train_b,
    float*       __restrict__ out)
{
    const unsigned b = blockIdx.x * blockDim.x + threadIdx.x;

    // last row: init acc, zero output
    const unsigned last = (unsigned)(T_STEPS - 1) * B_COLS + b;
    float acc = target_value[last];
    out[last] = 0.0f;

    // head: i = 254..249 (6 iterations) so the main loop is exact groups of 8
    acc = process_group<6>(T_STEPS - 2, b, acc,
                           reward, discount, value, target_value,
                           step_type, rollout_b, train_b, out);

    // main: i = 248..1 in 31 groups of 8
    for (int i = 248; i >= 8; i -= 8) {
        acc = process_group<8>(i, b, acc,
                               reward, discount, value, target_value,
                               step_type, rollout_b, train_b, out);
    }

    // peeled i = 0: is_last only affects acc (unused after), so skip flags
    {
        const unsigned idx1 = B_COLS + b;
        const float d   = discount[idx1] * GAMMA_F;
        const float r   = reward[idx1];
        const float ret = fmaf(acc, d, r);
        const float v   = value[b];
        const float diff = ret - v;
        out[b] = diff * diff;
    }
}

extern "C" void kernel_launch(void* const* d_in, const int* in_sizes, int n_in,
                              void* d_out, int out_size, void* d_ws, size_t ws_size,
                              hipStream_t stream) {
    const float* reward       = (const float*)d_in[0];
    const float* discount     = (const float*)d_in[1];
    const float* value        = (const float*)d_in[2];
    const float* target_value = (const float*)d_in[3];
    const int*   step_type    = (const int*)d_in[4];
    const int*   rollout_b    = (const int*)d_in[5];
    const int*   train_b      = (const int*)d_in[6];
    float*       out          = (float*)d_out;

    const int block = 256;
    const int grid  = B_COLS / block;  // 256 blocks, 1 per CU, 4 waves/CU
    td_loss_kernel<<<grid, block, 0, stream>>>(
        reward, discount, value, target_value, step_type, rollout_b, train_b, out);
}